// Round 14
// baseline (86.094 us; speedup 1.0000x reference)
//
#include <hip/hip_runtime.h>
#include <hip/hip_bf16.h>
#include <math.h>

// Problem dims (fixed)
#define BB 4
#define TT 4096
#define DM 1024
#define DS 256
#define MROWS (BB*TT)        // 16384

// Scan chunking
#define LCH 32
#define NCH (TT/LCH)         // 128

#define BM 128

typedef __attribute__((ext_vector_type(8))) _Float16 half8v;
typedef __attribute__((ext_vector_type(4))) float float4v;

__device__ __forceinline__ float sigmoidf_dev(float x) {
    return 1.0f / (1.0f + expf(-x));
}

// async global->LDS, 16 bytes per lane; dest linear (uniform + lane*16)
__device__ __forceinline__ void gload16(const void* g, void* l) {
    __builtin_amdgcn_global_load_lds(
        (const __attribute__((address_space(1))) void*)g,
        (__attribute__((address_space(3))) void*)l, 16, 0, 0);
}

// ---------------- input conversion (x + both weights, one launch) ----------------
// blocks [0,8192): x fp32 -> xf fp16 (8 elems/thread)
// blocks [8192,10240): W1/W2 fp32 [K][N] -> fp16 [N][K] transposed
__global__ __launch_bounds__(256) void cvt_inputs(
    const float* __restrict__ x, _Float16* __restrict__ xf,
    const float* __restrict__ W1, _Float16* __restrict__ T1,
    const float* __restrict__ W2, _Float16* __restrict__ T2)
{
    if (blockIdx.x < 8192) {
        size_t u = (size_t)blockIdx.x * 256 + threadIdx.x;   // unit = 8 elems
        const float* p = x + u * 8;
        float4 a = *(const float4*)p;
        float4 b = *(const float4*)(p + 4);
        half8v h;
        h[0] = (_Float16)a.x; h[1] = (_Float16)a.y; h[2] = (_Float16)a.z; h[3] = (_Float16)a.w;
        h[4] = (_Float16)b.x; h[5] = (_Float16)b.y; h[6] = (_Float16)b.z; h[7] = (_Float16)b.w;
        *(half8v*)(xf + u * 8) = h;
    } else {
        const int blk = blockIdx.x - 8192;
        const int half = blk >> 10;                          // 0: W_in, 1: W_out
        int idx = (blk & 1023) * 256 + threadIdx.x;          // over N*K = 262144
        const float* W = half ? W2 : W1;
        _Float16* T = half ? T2 : T1;
        const int K = half ? DS : DM;
        const int N = half ? DM : DS;
        int n = idx / K, k = idx - n * K;
        T[idx] = (_Float16)W[(size_t)k * N + n];
    }
}

// ---------------- GEMM1 (fused): gu = gamma*(xf @ w1t^T + b_in), + chunk partials --------
// A = xf fp16 [M][1024], Bt = w1t fp16 [256][1024], all staged via global_load_lds.
// 256 thr, 4 waves 2x2, tile 128x64, BK=64, NT=16.  (R11 champion config)
// Counted-vmcnt pipeline: 3 LDS buffers, 2 tiles in flight, vmcnt(6) per iter (never 0
// in steady state); raw s_barrier. 6 loads/stage (A 4 + B 2).
// LDS rows: 8 chunks x 16B; slot ch' = ch ^ (row&7)  (pre-swizzled source, same XOR read).
__global__ __launch_bounds__(256) void gemm1_fused(
    const _Float16* __restrict__ A, const _Float16* __restrict__ Bt,
    _Float16* __restrict__ gu,
    const float* __restrict__ bias, const float* __restrict__ scale,
    const float* __restrict__ lam, float* __restrict__ csum)
{
    constexpr int K = DM;        // 1024
    constexpr int BN = 64, BK = 64, NF = 2, WCOLS = 32;
    constexpr int NT = K / BK;   // 16
    constexpr int BUFB = 24576;  // A 16KB + B 8KB
    __shared__ char smem[3 * BUFB];      // 72KB; epilogue tile 34816 fits

    const int nwg = gridDim.x;                  // 512
    const int bid = blockIdx.x;
    const int wgid = (bid & 7) * (nwg >> 3) + (bid >> 3);
    const int GN = DS / BN;                     // 4
    const int bm = wgid / GN;
    const int bn = wgid - bm * GN;

    const int tid  = threadIdx.x;
    const int lane = tid & 63;
    const int wv   = tid >> 6;
    const int wr   = wv >> 1;
    const int wc   = wv & 1;
    const int lrow = lane & 15;
    const int q16  = lane >> 4;

    float4v acc[4][NF] = {};

#define STAGE1(T, Q)                                                              \
    do {                                                                          \
        char* base_ = smem + (Q) * BUFB;                                          \
        const int k0_ = (T) * BK;                                                 \
        _Pragma("unroll")                                                         \
        for (int p = 0; p < 4; p++) {                                             \
            int c = tid + p * 256, r = c >> 3, chp = c & 7;                       \
            const _Float16* g_ = A + (size_t)(bm * BM + r) * K + k0_              \
                                   + ((chp ^ (r & 7)) << 3);                      \
            gload16(g_, base_ + c * 16);                                          \
        }                                                                         \
        _Pragma("unroll")                                                         \
        for (int p = 0; p < 2; p++) {                                             \
            int c = tid + p * 256, r = c >> 3, chp = c & 7;                       \
            const _Float16* g_ = Bt + (size_t)(bn * BN + r) * K + k0_             \
                                    + ((chp ^ (r & 7)) << 3);                     \
            gload16(g_, base_ + 16384 + c * 16);                                  \
        }                                                                         \
    } while (0)

#define COMPUTE1(Q)                                                               \
    do {                                                                          \
        char* const rb = smem + (Q) * BUFB;                                       \
        half8v a[4][2], b[NF][2];                                                 \
        _Pragma("unroll")                                                         \
        for (int i = 0; i < 4; i++) {                                             \
            int row = wr * 64 + i * 16 + lrow;                                    \
            _Pragma("unroll")                                                     \
            for (int ss = 0; ss < 2; ss++) {                                      \
                int ch = (ss * 4 + q16) ^ (row & 7);                              \
                a[i][ss] = *(const half8v*)(rb + row * 128 + ch * 16);            \
            }                                                                     \
        }                                                                         \
        _Pragma("unroll")                                                         \
        for (int j = 0; j < NF; j++) {                                            \
            int row = wc * WCOLS + j * 16 + lrow;                                 \
            _Pragma("unroll")                                                     \
            for (int ss = 0; ss < 2; ss++) {                                      \
                int ch = (ss * 4 + q16) ^ (row & 7);                              \
                b[j][ss] = *(const half8v*)(rb + 16384 + row * 128 + ch * 16);    \
            }                                                                     \
        }                                                                         \
        _Pragma("unroll")                                                         \
        for (int ss = 0; ss < 2; ss++)                                            \
            _Pragma("unroll")                                                     \
            for (int i = 0; i < 4; i++)                                           \
                _Pragma("unroll")                                                 \
                for (int j = 0; j < NF; j++)                                      \
                    acc[i][j] = __builtin_amdgcn_mfma_f32_16x16x32_f16(           \
                        a[i][ss], b[j][ss], acc[i][j], 0, 0, 0);                  \
    } while (0)

    // prologue: 2 tiles in flight
    STAGE1(0, 0);
    STAGE1(1, 1);

    int qc = 0;
    for (int t = 0; t < NT - 1; ++t) {
        asm volatile("s_waitcnt vmcnt(6)" ::: "memory");   // tile t ready; t+1 in flight
        __builtin_amdgcn_s_barrier();
        if (t + 2 < NT) {
            int qn = qc + 2; if (qn >= 3) qn -= 3;
            STAGE1(t + 2, qn);
        }
        COMPUTE1(qc);
        qc = (qc == 2) ? 0 : qc + 1;
    }
    asm volatile("s_waitcnt vmcnt(0)" ::: "memory");
    __builtin_amdgcn_s_barrier();
    COMPUTE1(qc);
    __syncthreads();    // all waves done with LDS buffers before epilogue reuse

    // ---- epilogue: write gu (fp16) + stash tile in LDS for scan partials ----
    float* gul = (float*)smem;    // [128][68]
#pragma unroll
    for (int j = 0; j < NF; j++) {
        int col = bn * BN + wc * WCOLS + j * 16 + lrow;
        float bi = bias[col];
        float sc = scale[col];
#pragma unroll
        for (int i = 0; i < 4; i++) {
            int r0 = bm * BM + wr * 64 + i * 16 + q16 * 4;
#pragma unroll
            for (int reg = 0; reg < 4; reg++) {
                float v = (acc[i][j][reg] + bi) * sc;
                gu[(size_t)(r0 + reg) * DS + col] = (_Float16)v;
                int lr = wr * 64 + i * 16 + q16 * 4 + reg;
                int lc = wc * WCOLS + j * 16 + lrow;
                gul[lr * 68 + lc] = v;
            }
        }
    }

    __syncthreads();
    // 256 threads: one (chunk, channel) scan each; BM=128 -> 4 chunks of 32.
    const int lc = tid >> 6;
    const int ch = tid & 63;
    const int gcol = bn * BN + ch;
    const float d = sigmoidf_dev(lam[gcol]);
    float h = 0.0f;
#pragma unroll
    for (int rr = 0; rr < LCH; rr++)
        h = fmaf(d, h, gul[(lc * LCH + rr) * 68 + ch]);
    const int row0 = bm * BM;
    const int b    = row0 >> 12;
    const int gch  = ((row0 & 4095) >> 5) + lc;
    csum[((size_t)b * NCH + gch) * DS + gcol] = h;
#undef STAGE1
#undef COMPUTE1
}

// ---------------- fused scan: per-block carry prefix + chunk scan ----------------
// Block (chunk, b): carry-in computed by redundant prefix over csum[k<chunk]
// (identical fma order to the old carry_scan -> bit-identical), then local scan
// of gu -> hf. Last-chunk blocks write hlast. Replaces carry_scan + scan_final.
__global__ __launch_bounds__(256) void scan_fused(
    const _Float16* __restrict__ gu, const float* __restrict__ csum,
    const float* __restrict__ state, const float* __restrict__ lam,
    _Float16* __restrict__ hf, float* __restrict__ hlast)
{
    const int s = threadIdx.x;
    const int chunk = blockIdx.x;     // 0..NCH-1
    const int b = blockIdx.y;
    const float d = sigmoidf_dev(lam[s]);
    float dL = d;
#pragma unroll
    for (int i = 0; i < 5; i++) dL *= dL;   // d^32

    // carry-in: prefix over csum[0..chunk)
    float H = state[(size_t)b * DS + s];
    const float* cp = csum + (size_t)b * NCH * DS + s;
    for (int k = 0; k < chunk; ++k)
        H = fmaf(dL, H, cp[(size_t)k * DS]);

    // local scan with carry-in
    const size_t base = ((size_t)b * TT + (size_t)chunk * LCH) * DS + s;
    const _Float16* p = gu + base;
    _Float16* ph = hf + base;
    float h = H;
#pragma unroll
    for (int t = 0; t < LCH; t++) {
        h = fmaf(d, h, (float)p[(size_t)t * DS]);
        ph[(size_t)t * DS] = (_Float16)h;
    }
    if (chunk == NCH - 1)
        hlast[(size_t)b * DS + s] = h;
}

// ---------------- GEMM2: y = h @ W_out + b_out ----------------
// A = hf fp16 [M][256], Bt = w2t fp16 [1024][256]. Tile 128x128, BK=32, NT=8.
// Counted-vmcnt pipeline (R11-proven): 3 buffers x 16KB, 4 loads/stage, vmcnt(4).
__global__ __launch_bounds__(256) void gemm2_f16(
    const _Float16* __restrict__ A, const _Float16* __restrict__ Bt,
    float* __restrict__ C, const float* __restrict__ bias)
{
    constexpr int BN = 128, BK = 32, NF = 4, WCOLS = 64;
    constexpr int K = DS;                         // 256
    constexpr int NT = K / BK;                    // 8
    constexpr int BUFB = 16384;                   // A 8KB + B 8KB
    __shared__ char smem[3 * BUFB];               // 48KB

    const int nwg = gridDim.x;                    // 1024
    const int bid = blockIdx.x;
    const int wgid = (bid & 7) * (nwg >> 3) + (bid >> 3);
    const int GN = DM / BN;                       // 8
    const int bm = wgid / GN;
    const int bn = wgid - bm * GN;

    const int tid  = threadIdx.x;
    const int lane = tid & 63;
    const int wv   = tid >> 6;
    const int wr   = wv >> 1;
    const int wc   = wv & 1;
    const int lrow = lane & 15;
    const int q16  = lane >> 4;

    float4v acc[4][NF] = {};

#define STAGE2(T, Q)                                                              \
    do {                                                                          \
        char* base_ = smem + (Q) * BUFB;                                          \
        const int k0_ = (T) * BK;                                                 \
        _Pragma("unroll")                                                         \
        for (int p = 0; p < 2; p++) {                                             \
            int c = tid + p * 256, r = c >> 2, chp = c & 3;                       \
            const _Float16* g_ = A + (size_t)(bm * BM + r) * K + k0_              \
                                   + ((chp ^ ((r >> 1) & 3)) << 3);               \
            gload16(g_, base_ + c * 16);                                          \
        }                                                                         \
        _Pragma("unroll")                                                         \
        for (int p = 0; p < 2; p++) {                                             \
            int c = tid + p * 256, r = c >> 2, chp = c & 3;                       \
            const _Float16* g_ = Bt + (size_t)(bn * BN + r) * K + k0_             \
                                    + ((chp ^ ((r >> 1) & 3)) << 3);              \
            gload16(g_, base_ + 8192 + c * 16);                                   \
        }                                                                         \
    } while (0)

#define COMPUTE2(Q)                                                               \
    do {                                                                          \
        char* const rb = smem + (Q) * BUFB;                                       \
        half8v a[4], b[NF];                                                       \
        _Pragma("unroll")                                                         \
        for (int i = 0; i < 4; i++) {                                             \
            int row = wr * 64 + i * 16 + lrow;                                    \
            int ch = q16 ^ ((row >> 1) & 3);                                      \
            a[i] = *(const half8v*)(rb + row * 64 + ch * 16);                     \
        }                                                                         \
        _Pragma("unroll")                                                         \
        for (int j = 0; j < NF; j++) {                                            \
            int row = wc * WCOLS + j * 16 + lrow;                                 \
            int ch = q16 ^ ((row >> 1) & 3);                                      \
            b[j] = *(const half8v*)(rb + 8192 + row * 64 + ch * 16);              \
        }                                                                         \
        _Pragma("unroll")                                                         \
        for (int i = 0; i < 4; i++)                                               \
            _Pragma("unroll")                                                     \
            for (int j = 0; j < NF; j++)                                          \
                acc[i][j] = __builtin_amdgcn_mfma_f32_16x16x32_f16(               \
                    a[i], b[j], acc[i][j], 0, 0, 0);                              \
    } while (0)

    STAGE2(0, 0);
    STAGE2(1, 1);

    int qc = 0;
    for (int t = 0; t < NT - 1; ++t) {
        asm volatile("s_waitcnt vmcnt(4)" ::: "memory");
        __builtin_amdgcn_s_barrier();
        if (t + 2 < NT) {
            int qn = qc + 2; if (qn >= 3) qn -= 3;
            STAGE2(t + 2, qn);
        }
        COMPUTE2(qc);
        qc = (qc == 2) ? 0 : qc + 1;
    }
    asm volatile("s_waitcnt vmcnt(0)" ::: "memory");
    __builtin_amdgcn_s_barrier();
    COMPUTE2(qc);

#pragma unroll
    for (int j = 0; j < NF; j++) {
        int col = bn * BN + wc * WCOLS + j * 16 + lrow;
        float bi = bias[col];
#pragma unroll
        for (int i = 0; i < 4; i++) {
            int r0 = bm * BM + wr * 64 + i * 16 + q16 * 4;
#pragma unroll
            for (int reg = 0; reg < 4; reg++)
                C[(size_t)(r0 + reg) * DM + col] = acc[i][j][reg] + bi;
        }
    }
#undef STAGE2
#undef COMPUTE2
}

extern "C" void kernel_launch(void* const* d_in, const int* in_sizes, int n_in,
                              void* d_out, int out_size, void* d_ws, size_t ws_size,
                              hipStream_t stream) {
    const float* x     = (const float*)d_in[0];
    const float* state = (const float*)d_in[1];
    const float* W_in  = (const float*)d_in[2];
    const float* b_in  = (const float*)d_in[3];
    const float* lam   = (const float*)d_in[4];
    const float* gamma = (const float*)d_in[5];
    const float* W_out = (const float*)d_in[6];
    const float* b_out = (const float*)d_in[7];

    float* y     = (float*)d_out;
    float* hlast = y + (size_t)MROWS * DM;

    char* ws = (char*)d_ws;
    const size_t MB = 1024 * 1024;
    _Float16*  gu    = (_Float16*)(ws);                        // 8 MB  [M][DS]
    float*     csum  = (float*)(ws + 8 * MB);                  // 512 KB
    _Float16*  hf    = (_Float16*)(ws + 9 * MB);               // 8 MB  [M][DS]
    _Float16*  w1t   = (_Float16*)(ws + 17 * MB);              // 512 KB [DS][DM]
    _Float16*  w2t   = (_Float16*)(ws + 17 * MB + 512 * 1024); // 512 KB [DM][DS]
    _Float16*  xf    = (_Float16*)(ws + 18 * MB);              // 32 MB [M][DM]

    cvt_inputs<<<dim3(10240), dim3(256), 0, stream>>>(x, xf, W_in, w1t, W_out, w2t);

    // GEMM1 (+fused chunk partials), counted-vmcnt pipeline
    gemm1_fused<<<dim3((MROWS / BM) * (DS / 64)), dim3(256), 0, stream>>>(
        xf, w1t, gu, b_in, gamma, lam, csum);

    // fused carry-prefix + chunk scan (replaces carry_scan + scan_final)
    scan_fused<<<dim3(NCH, BB), dim3(256), 0, stream>>>(gu, csum, state, lam, hf, hlast);

    // GEMM2: y = h @ W_out + b_out, counted-vmcnt pipeline
    gemm2_f16<<<dim3((MROWS / BM) * (DM / 128)), dim3(256), 0, stream>>>(
        hf, w2t, y, b_out);
}

// Round 15
// 63.029 us; speedup vs baseline: 1.3659x; 1.3659x over previous
//
#include <hip/hip_runtime.h>
#include <hip/hip_bf16.h>
#include <math.h>

// Problem dims (fixed)
#define BB 4
#define TT 4096
#define DM 1024
#define DS 256
#define MROWS (BB*TT)        // 16384

// Scan chunking
#define LCH 32
#define NCH (TT/LCH)         // 128

#define BM 128

typedef __attribute__((ext_vector_type(8))) _Float16 half8v;
typedef __attribute__((ext_vector_type(4))) float float4v;

__device__ __forceinline__ float sigmoidf_dev(float x) {
    return 1.0f / (1.0f + expf(-x));
}

// async global->LDS, 16 bytes per lane; dest linear (uniform + lane*16)
__device__ __forceinline__ void gload16(const void* g, void* l) {
    __builtin_amdgcn_global_load_lds(
        (const __attribute__((address_space(1))) void*)g,
        (__attribute__((address_space(3))) void*)l, 16, 0, 0);
}

// ---------------- input conversion (x + both weights, one launch) ----------------
// blocks [0,8192): x fp32 -> xf fp16 (8 elems/thread)
// blocks [8192,10240): W1/W2 fp32 [K][N] -> fp16 [N][K] transposed
__global__ __launch_bounds__(256) void cvt_inputs(
    const float* __restrict__ x, _Float16* __restrict__ xf,
    const float* __restrict__ W1, _Float16* __restrict__ T1,
    const float* __restrict__ W2, _Float16* __restrict__ T2)
{
    if (blockIdx.x < 8192) {
        size_t u = (size_t)blockIdx.x * 256 + threadIdx.x;   // unit = 8 elems
        const float* p = x + u * 8;
        float4 a = *(const float4*)p;
        float4 b = *(const float4*)(p + 4);
        half8v h;
        h[0] = (_Float16)a.x; h[1] = (_Float16)a.y; h[2] = (_Float16)a.z; h[3] = (_Float16)a.w;
        h[4] = (_Float16)b.x; h[5] = (_Float16)b.y; h[6] = (_Float16)b.z; h[7] = (_Float16)b.w;
        *(half8v*)(xf + u * 8) = h;
    } else {
        const int blk = blockIdx.x - 8192;
        const int half = blk >> 10;                          // 0: W_in, 1: W_out
        int idx = (blk & 1023) * 256 + threadIdx.x;          // over N*K = 262144
        const float* W = half ? W2 : W1;
        _Float16* T = half ? T2 : T1;
        const int K = half ? DS : DM;
        const int N = half ? DM : DS;
        int n = idx / K, k = idx - n * K;
        T[idx] = (_Float16)W[(size_t)k * N + n];
    }
}

// ---------------- GEMM1 (fused): gu = gamma*(xf @ w1t^T + b_in), + chunk partials --------
// A = xf fp16 [M][1024], Bt = w1t fp16 [256][1024], all staged via global_load_lds.
// 256 thr, 4 waves 2x2, tile 128x64, BK=64, NT=16.  (R11 champion config)
// Counted-vmcnt pipeline: 3 LDS buffers, 2 tiles in flight, vmcnt(6) per iter (never 0
// in steady state); raw s_barrier. 6 loads/stage (A 4 + B 2).
// LDS rows: 8 chunks x 16B; slot ch' = ch ^ (row&7)  (pre-swizzled source, same XOR read).
__global__ __launch_bounds__(256) void gemm1_fused(
    const _Float16* __restrict__ A, const _Float16* __restrict__ Bt,
    _Float16* __restrict__ gu,
    const float* __restrict__ bias, const float* __restrict__ scale,
    const float* __restrict__ lam, float* __restrict__ csum)
{
    constexpr int K = DM;        // 1024
    constexpr int BN = 64, BK = 64, NF = 2, WCOLS = 32;
    constexpr int NT = K / BK;   // 16
    constexpr int BUFB = 24576;  // A 16KB + B 8KB
    __shared__ char smem[3 * BUFB];      // 72KB; epilogue tile 34816 fits

    const int nwg = gridDim.x;                  // 512
    const int bid = blockIdx.x;
    const int wgid = (bid & 7) * (nwg >> 3) + (bid >> 3);
    const int GN = DS / BN;                     // 4
    const int bm = wgid / GN;
    const int bn = wgid - bm * GN;

    const int tid  = threadIdx.x;
    const int lane = tid & 63;
    const int wv   = tid >> 6;
    const int wr   = wv >> 1;
    const int wc   = wv & 1;
    const int lrow = lane & 15;
    const int q16  = lane >> 4;

    float4v acc[4][NF] = {};

#define STAGE1(T, Q)                                                              \
    do {                                                                          \
        char* base_ = smem + (Q) * BUFB;                                          \
        const int k0_ = (T) * BK;                                                 \
        _Pragma("unroll")                                                         \
        for (int p = 0; p < 4; p++) {                                             \
            int c = tid + p * 256, r = c >> 3, chp = c & 7;                       \
            const _Float16* g_ = A + (size_t)(bm * BM + r) * K + k0_              \
                                   + ((chp ^ (r & 7)) << 3);                      \
            gload16(g_, base_ + c * 16);                                          \
        }                                                                         \
        _Pragma("unroll")                                                         \
        for (int p = 0; p < 2; p++) {                                             \
            int c = tid + p * 256, r = c >> 3, chp = c & 7;                       \
            const _Float16* g_ = Bt + (size_t)(bn * BN + r) * K + k0_             \
                                    + ((chp ^ (r & 7)) << 3);                     \
            gload16(g_, base_ + 16384 + c * 16);                                  \
        }                                                                         \
    } while (0)

#define COMPUTE1(Q)                                                               \
    do {                                                                          \
        char* const rb = smem + (Q) * BUFB;                                       \
        half8v a[4][2], b[NF][2];                                                 \
        _Pragma("unroll")                                                         \
        for (int i = 0; i < 4; i++) {                                             \
            int row = wr * 64 + i * 16 + lrow;                                    \
            _Pragma("unroll")                                                     \
            for (int ss = 0; ss < 2; ss++) {                                      \
                int ch = (ss * 4 + q16) ^ (row & 7);                              \
                a[i][ss] = *(const half8v*)(rb + row * 128 + ch * 16);            \
            }                                                                     \
        }                                                                         \
        _Pragma("unroll")                                                         \
        for (int j = 0; j < NF; j++) {                                            \
            int row = wc * WCOLS + j * 16 + lrow;                                 \
            _Pragma("unroll")                                                     \
            for (int ss = 0; ss < 2; ss++) {                                      \
                int ch = (ss * 4 + q16) ^ (row & 7);                              \
                b[j][ss] = *(const half8v*)(rb + 16384 + row * 128 + ch * 16);    \
            }                                                                     \
        }                                                                         \
        _Pragma("unroll")                                                         \
        for (int ss = 0; ss < 2; ss++)                                            \
            _Pragma("unroll")                                                     \
            for (int i = 0; i < 4; i++)                                           \
                _Pragma("unroll")                                                 \
                for (int j = 0; j < NF; j++)                                      \
                    acc[i][j] = __builtin_amdgcn_mfma_f32_16x16x32_f16(           \
                        a[i][ss], b[j][ss], acc[i][j], 0, 0, 0);                  \
    } while (0)

    // prologue: 2 tiles in flight
    STAGE1(0, 0);
    STAGE1(1, 1);

    int qc = 0;
    for (int t = 0; t < NT - 1; ++t) {
        asm volatile("s_waitcnt vmcnt(6)" ::: "memory");   // tile t ready; t+1 in flight
        __builtin_amdgcn_s_barrier();
        if (t + 2 < NT) {
            int qn = qc + 2; if (qn >= 3) qn -= 3;
            STAGE1(t + 2, qn);
        }
        COMPUTE1(qc);
        qc = (qc == 2) ? 0 : qc + 1;
    }
    asm volatile("s_waitcnt vmcnt(0)" ::: "memory");
    __builtin_amdgcn_s_barrier();
    COMPUTE1(qc);
    __syncthreads();    // all waves done with LDS buffers before epilogue reuse

    // ---- epilogue: write gu (fp16) + stash tile in LDS for scan partials ----
    float* gul = (float*)smem;    // [128][68]
#pragma unroll
    for (int j = 0; j < NF; j++) {
        int col = bn * BN + wc * WCOLS + j * 16 + lrow;
        float bi = bias[col];
        float sc = scale[col];
#pragma unroll
        for (int i = 0; i < 4; i++) {
            int r0 = bm * BM + wr * 64 + i * 16 + q16 * 4;
#pragma unroll
            for (int reg = 0; reg < 4; reg++) {
                float v = (acc[i][j][reg] + bi) * sc;
                gu[(size_t)(r0 + reg) * DS + col] = (_Float16)v;
                int lr = wr * 64 + i * 16 + q16 * 4 + reg;
                int lc = wc * WCOLS + j * 16 + lrow;
                gul[lr * 68 + lc] = v;
            }
        }
    }

    __syncthreads();
    // 256 threads: one (chunk, channel) scan each; BM=128 -> 4 chunks of 32.
    const int lc = tid >> 6;
    const int ch = tid & 63;
    const int gcol = bn * BN + ch;
    const float d = sigmoidf_dev(lam[gcol]);
    float h = 0.0f;
#pragma unroll
    for (int rr = 0; rr < LCH; rr++)
        h = fmaf(d, h, gul[(lc * LCH + rr) * 68 + ch]);
    const int row0 = bm * BM;
    const int b    = row0 >> 12;
    const int gch  = ((row0 & 4095) >> 5) + lc;
    csum[((size_t)b * NCH + gch) * DS + gcol] = h;
#undef STAGE1
#undef COMPUTE1
}

// ---------------- fused scan: batched carry prefix + chunk scan ----------------
// Block (chunk, b): carry-in = prefix over csum[0..chunk), strip-mined x8 so each
// group issues 8 INDEPENDENT loads before its 8 chained fmas (R14 lesson: a runtime
// serial load+fma chain exposes full latency per iter). Same fma order as the old
// carry_scan -> identical numerics. Last-chunk blocks write hlast.
__global__ __launch_bounds__(256) void scan_fused(
    const _Float16* __restrict__ gu, const float* __restrict__ csum,
    const float* __restrict__ state, const float* __restrict__ lam,
    _Float16* __restrict__ hf, float* __restrict__ hlast)
{
    const int s = threadIdx.x;
    const int chunk = blockIdx.x;     // 0..NCH-1
    const int b = blockIdx.y;
    const float d = sigmoidf_dev(lam[s]);
    float dL = d;
#pragma unroll
    for (int i = 0; i < 5; i++) dL *= dL;   // d^32

    float H = state[(size_t)b * DS + s];
    const float* cp = csum + (size_t)b * NCH * DS + s;
    int k = 0;
    for (; k + 8 <= chunk; k += 8) {
        float v0 = cp[(size_t)(k + 0) * DS];
        float v1 = cp[(size_t)(k + 1) * DS];
        float v2 = cp[(size_t)(k + 2) * DS];
        float v3 = cp[(size_t)(k + 3) * DS];
        float v4 = cp[(size_t)(k + 4) * DS];
        float v5 = cp[(size_t)(k + 5) * DS];
        float v6 = cp[(size_t)(k + 6) * DS];
        float v7 = cp[(size_t)(k + 7) * DS];
        H = fmaf(dL, H, v0); H = fmaf(dL, H, v1);
        H = fmaf(dL, H, v2); H = fmaf(dL, H, v3);
        H = fmaf(dL, H, v4); H = fmaf(dL, H, v5);
        H = fmaf(dL, H, v6); H = fmaf(dL, H, v7);
    }
    for (; k < chunk; ++k)
        H = fmaf(dL, H, cp[(size_t)k * DS]);

    // local scan with carry-in
    const size_t base = ((size_t)b * TT + (size_t)chunk * LCH) * DS + s;
    const _Float16* p = gu + base;
    _Float16* ph = hf + base;
    float h = H;
#pragma unroll
    for (int t = 0; t < LCH; t++) {
        h = fmaf(d, h, (float)p[(size_t)t * DS]);
        ph[(size_t)t * DS] = (_Float16)h;
    }
    if (chunk == NCH - 1)
        hlast[(size_t)b * DS + s] = h;
}

// ---------------- GEMM2: y = h @ W_out + b_out ----------------
// A = hf fp16 [M][256], Bt = w2t fp16 [1024][256]. Tile 128x128, BK=32, NT=8.
// Counted-vmcnt pipeline (R11-proven): 3 buffers x 16KB, 4 loads/stage, vmcnt(4).
__global__ __launch_bounds__(256) void gemm2_f16(
    const _Float16* __restrict__ A, const _Float16* __restrict__ Bt,
    float* __restrict__ C, const float* __restrict__ bias)
{
    constexpr int BN = 128, BK = 32, NF = 4, WCOLS = 64;
    constexpr int K = DS;                         // 256
    constexpr int NT = K / BK;                    // 8
    constexpr int BUFB = 16384;                   // A 8KB + B 8KB
    __shared__ char smem[3 * BUFB];               // 48KB

    const int nwg = gridDim.x;                    // 1024
    const int bid = blockIdx.x;
    const int wgid = (bid & 7) * (nwg >> 3) + (bid >> 3);
    const int GN = DM / BN;                       // 8
    const int bm = wgid / GN;
    const int bn = wgid - bm * GN;

    const int tid  = threadIdx.x;
    const int lane = tid & 63;
    const int wv   = tid >> 6;
    const int wr   = wv >> 1;
    const int wc   = wv & 1;
    const int lrow = lane & 15;
    const int q16  = lane >> 4;

    float4v acc[4][NF] = {};

#define STAGE2(T, Q)                                                              \
    do {                                                                          \
        char* base_ = smem + (Q) * BUFB;                                          \
        const int k0_ = (T) * BK;                                                 \
        _Pragma("unroll")                                                         \
        for (int p = 0; p < 2; p++) {                                             \
            int c = tid + p * 256, r = c >> 2, chp = c & 3;                       \
            const _Float16* g_ = A + (size_t)(bm * BM + r) * K + k0_              \
                                   + ((chp ^ ((r >> 1) & 3)) << 3);               \
            gload16(g_, base_ + c * 16);                                          \
        }                                                                         \
        _Pragma("unroll")                                                         \
        for (int p = 0; p < 2; p++) {                                             \
            int c = tid + p * 256, r = c >> 2, chp = c & 3;                       \
            const _Float16* g_ = Bt + (size_t)(bn * BN + r) * K + k0_             \
                                    + ((chp ^ ((r >> 1) & 3)) << 3);              \
            gload16(g_, base_ + 8192 + c * 16);                                   \
        }                                                                         \
    } while (0)

#define COMPUTE2(Q)                                                              \
    do {                                                                          \
        char* const rb = smem + (Q) * BUFB;                                       \
        half8v a[4], b[NF];                                                       \
        _Pragma("unroll")                                                         \
        for (int i = 0; i < 4; i++) {                                             \
            int row = wr * 64 + i * 16 + lrow;                                    \
            int ch = q16 ^ ((row >> 1) & 3);                                      \
            a[i] = *(const half8v*)(rb + row * 64 + ch * 16);                     \
        }                                                                         \
        _Pragma("unroll")                                                         \
        for (int j = 0; j < NF; j++) {                                            \
            int row = wc * WCOLS + j * 16 + lrow;                                 \
            int ch = q16 ^ ((row >> 1) & 3);                                      \
            b[j] = *(const half8v*)(rb + 8192 + row * 64 + ch * 16);              \
        }                                                                         \
        _Pragma("unroll")                                                         \
        for (int i = 0; i < 4; i++)                                               \
            _Pragma("unroll")                                                     \
            for (int j = 0; j < NF; j++)                                          \
                acc[i][j] = __builtin_amdgcn_mfma_f32_16x16x32_f16(               \
                    a[i], b[j], acc[i][j], 0, 0, 0);                              \
    } while (0)

    STAGE2(0, 0);
    STAGE2(1, 1);

    int qc = 0;
    for (int t = 0; t < NT - 1; ++t) {
        asm volatile("s_waitcnt vmcnt(4)" ::: "memory");
        __builtin_amdgcn_s_barrier();
        if (t + 2 < NT) {
            int qn = qc + 2; if (qn >= 3) qn -= 3;
            STAGE2(t + 2, qn);
        }
        COMPUTE2(qc);
        qc = (qc == 2) ? 0 : qc + 1;
    }
    asm volatile("s_waitcnt vmcnt(0)" ::: "memory");
    __builtin_amdgcn_s_barrier();
    COMPUTE2(qc);

#pragma unroll
    for (int j = 0; j < NF; j++) {
        int col = bn * BN + wc * WCOLS + j * 16 + lrow;
        float bi = bias[col];
#pragma unroll
        for (int i = 0; i < 4; i++) {
            int r0 = bm * BM + wr * 64 + i * 16 + q16 * 4;
#pragma unroll
            for (int reg = 0; reg < 4; reg++)
                C[(size_t)(r0 + reg) * DM + col] = acc[i][j][reg] + bi;
        }
    }
#undef STAGE2
#undef COMPUTE2
}

extern "C" void kernel_launch(void* const* d_in, const int* in_sizes, int n_in,
                              void* d_out, int out_size, void* d_ws, size_t ws_size,
                              hipStream_t stream) {
    const float* x     = (const float*)d_in[0];
    const float* state = (const float*)d_in[1];
    const float* W_in  = (const float*)d_in[2];
    const float* b_in  = (const float*)d_in[3];
    const float* lam   = (const float*)d_in[4];
    const float* gamma = (const float*)d_in[5];
    const float* W_out = (const float*)d_in[6];
    const float* b_out = (const float*)d_in[7];

    float* y     = (float*)d_out;
    float* hlast = y + (size_t)MROWS * DM;

    char* ws = (char*)d_ws;
    const size_t MB = 1024 * 1024;
    _Float16*  gu    = (_Float16*)(ws);                        // 8 MB  [M][DS]
    float*     csum  = (float*)(ws + 8 * MB);                  // 512 KB
    _Float16*  hf    = (_Float16*)(ws + 9 * MB);               // 8 MB  [M][DS]
    _Float16*  w1t   = (_Float16*)(ws + 17 * MB);              // 512 KB [DS][DM]
    _Float16*  w2t   = (_Float16*)(ws + 17 * MB + 512 * 1024); // 512 KB [DM][DS]
    _Float16*  xf    = (_Float16*)(ws + 18 * MB);              // 32 MB [M][DM]

    cvt_inputs<<<dim3(10240), dim3(256), 0, stream>>>(x, xf, W_in, w1t, W_out, w2t);

    // GEMM1 (+fused chunk partials), counted-vmcnt pipeline
    gemm1_fused<<<dim3((MROWS / BM) * (DS / 64)), dim3(256), 0, stream>>>(
        xf, w1t, gu, b_in, gamma, lam, csum);

    // fused batched carry-prefix + chunk scan (replaces carry_scan + scan_final)
    scan_fused<<<dim3(NCH, BB), dim3(256), 0, stream>>>(gu, csum, state, lam, hf, hlast);

    // GEMM2: y = h @ W_out + b_out, counted-vmcnt pipeline
    gemm2_f16<<<dim3((MROWS / BM) * (DM / 128)), dim3(256), 0, stream>>>(
        hf, w2t, y, b_out);
}